// Round 17
// baseline (53.459 us; speedup 1.0000x reference)
//
#include <hip/hip_runtime.h>
#include <hip/hip_fp16.h>
#include <math.h>

#define BB 8
#define HH 480
#define WW 640
#define CC 5
#define HW (HH * WW)
#define NBLK 300   // k_main blocks per image
#define NST 21     // accumulators per block

// d_ws layout:
// [0 .. 4096)                  : stats doubles: stats[b*NST + i]
// [PARTIAL_OFFSET, +2400*32*4) : per-block float partials [b*NBLK+bx][32]
// [GRAY2_OFFSET, +BB*HW*2)     : fp16 gray2 planes
// stat indices per b:
//  0=l1  1=mask  2=Sposm  3=Snegm  4=Sposm2  5=Snegm2
//  6..10 = Sgm[c]   11..15 = Sgm2[c]   16..20 = Spg[c]
#define PARTIAL_OFFSET 4096
#define GRAY2_OFFSET (PARTIAL_OFFSET + 2400 * 32 * 4)

// clang ext-vector type is accepted by the nontemporal builtins
typedef float vfloat4 __attribute__((ext_vector_type(4)));

__device__ __forceinline__ float4 ntload4(const float* p) {
    vfloat4 v = __builtin_nontemporal_load((const vfloat4*)p);
    return make_float4(v.x, v.y, v.z, v.w);
}
__device__ __forceinline__ void ntstore4(float* p, float4 v) {
    vfloat4 t = { v.x, v.y, v.z, v.w };
    __builtin_nontemporal_store(t, (vfloat4*)p);
}
__device__ __forceinline__ void ntstore1(float* p, float v) {
    __builtin_nontemporal_store(v, p);
}

__device__ __forceinline__ float fast_tanh5(float d) {
    // tanh(5d) = (1 - e^{-10d}) / (1 + e^{-10d})
    float ez = __expf(-10.0f * d);
    return (1.0f - ez) * __builtin_amdgcn_rcpf(1.0f + ez);
}

__device__ __forceinline__ float mixc(int c, float pos, float neg) {
    if (c == 0) return pos;
    if (c == 1) return neg;
    const float w = 0.25f * (float)(c - 1);
    return w * pos + (1.0f - w) * neg;
}

// Full-wave (64-lane) sum via DPP. Total lands in lane 63.
__device__ __forceinline__ float wave_sum_dpp(float v) {
    v += __int_as_float(__builtin_amdgcn_update_dpp(0, __float_as_int(v), 0x111, 0xf, 0xf, false));
    v += __int_as_float(__builtin_amdgcn_update_dpp(0, __float_as_int(v), 0x112, 0xf, 0xf, false));
    v += __int_as_float(__builtin_amdgcn_update_dpp(0, __float_as_int(v), 0x114, 0xf, 0xf, false));
    v += __int_as_float(__builtin_amdgcn_update_dpp(0, __float_as_int(v), 0x118, 0xf, 0xf, false));
    v += __int_as_float(__builtin_amdgcn_update_dpp(0, __float_as_int(v), 0x142, 0xa, 0xf, false));
    v += __int_as_float(__builtin_amdgcn_update_dpp(0, __float_as_int(v), 0x143, 0xc, 0xf, false));
    return v;
}

// 1200 blocks, XCD-swizzled (b = blk&7): image b's gray2 lands in XCD b's L2.
// img2 read is streaming -> nontemporal; gray2h write stays cached (gathered next).
__global__ __launch_bounds__(256) void k_gray2(const float* __restrict__ img2,
                                               __half* __restrict__ gray2h) {
    const int phys = blockIdx.x;
    const int b = phys & 7;
    const int j = phys >> 3;                       // [0,150)
    const int p8 = j * 2048 + threadIdx.x * 8;     // plane offset, 8 px
    const float* src = img2 + (size_t)b * 3 * HW + p8;
    float4 r0 = ntload4(src);
    float4 r1 = ntload4(src + 4);
    float4 g0 = ntload4(src + HW);
    float4 g1 = ntload4(src + HW + 4);
    float4 b0 = ntload4(src + 2 * HW);
    float4 b1 = ntload4(src + 2 * HW + 4);
    __half o[8];
    o[0] = __float2half(0.299f * r0.x + 0.587f * g0.x + 0.114f * b0.x);
    o[1] = __float2half(0.299f * r0.y + 0.587f * g0.y + 0.114f * b0.y);
    o[2] = __float2half(0.299f * r0.z + 0.587f * g0.z + 0.114f * b0.z);
    o[3] = __float2half(0.299f * r0.w + 0.587f * g0.w + 0.114f * b0.w);
    o[4] = __float2half(0.299f * r1.x + 0.587f * g1.x + 0.114f * b1.x);
    o[5] = __float2half(0.299f * r1.y + 0.587f * g1.y + 0.114f * b1.y);
    o[6] = __float2half(0.299f * r1.z + 0.587f * g1.z + 0.114f * b1.z);
    o[7] = __float2half(0.299f * r1.w + 0.587f * g1.w + 0.114f * b1.w);
    *(uint4*)(gray2h + (size_t)b * HW + p8) = *(const uint4*)o;
}

// 2400 blocks 1D, XCD-swizzled: b = blk&7, bx = blk>>3.
// ALL streaming traffic (flow/img1/vmask/ev reads, pred writes) is nontemporal
// -> L2 reserved for the gray2h gather working set (600 KB/image).
__global__ __launch_bounds__(256, 2) void k_main(
    const float* __restrict__ img1, const float* __restrict__ flow,
    const float* __restrict__ ev, const float* __restrict__ vmask,
    const __half* __restrict__ gray2h, float* __restrict__ pred_out,
    float* __restrict__ partial)
{
    const int b  = blockIdx.x & 7;
    const int bx = blockIdx.x >> 3;               // [0,300)
    const float* i1  = img1  + (size_t)b * 3 * HW;
    const float* fl  = flow  + (size_t)b * 2 * HW;
    const float* evb = ev    + (size_t)b * CC * HW;
    const float* vm  = vmask + (size_t)b * HW;
    const __half* g2 = gray2h + (size_t)b * HW;
    float* po = pred_out + (size_t)b * CC * HW;   // NOTE: 4B-aligned only (out+1)

    const int tid = threadIdx.x;
    const int P   = bx * 1024;                    // block owns px [P, P+1024)
    const int p4  = P + 4 * tid;                  // 4 px, same row
    const int py  = p4 / WW;
    const int px0 = p4 - py * WW;

    __shared__ float sdata[4][NST];

    // ---- phase 1: flow loads (gather addresses depend only on these) ----
    float4 fx4 = ntload4(fl + p4);
    float4 fy4 = ntload4(fl + HW + p4);

    float fxa[4] = { fx4.x, fx4.y, fx4.z, fx4.w };
    float fya[4] = { fy4.x, fy4.y, fy4.z, fy4.w };

    int   adr[16];
    float wgt[16];
#pragma unroll
    for (int j = 0; j < 4; ++j) {
        float fx = fxa[j], fy = fya[j];
        float x = (float)(px0 + j) + fx;
        float y = (float)py + fy;
        float x0f = floorf(x);
        float y0f = floorf(y);
        float wx = x - x0f;
        float wy = y - y0f;
        int x0 = (int)x0f, y0 = (int)y0f;
        int x1 = x0 + 1,   y1 = y0 + 1;
        int cx0 = min(max(x0, 0), WW - 1);
        int cx1 = min(max(x1, 0), WW - 1);
        int cy0 = min(max(y0, 0), HH - 1);
        int cy1 = min(max(y1, 0), HH - 1);
        float wx0 = (1.0f - wx) * ((x0 >= 0 && x0 < WW) ? 1.0f : 0.0f);
        float wx1 = wx          * ((x1 >= 0 && x1 < WW) ? 1.0f : 0.0f);
        float wy0 = (1.0f - wy) * ((y0 >= 0 && y0 < HH) ? 1.0f : 0.0f);
        float wy1 = wy          * ((y1 >= 0 && y1 < HH) ? 1.0f : 0.0f);
        adr[j*4+0] = cy0 * WW + cx0;
        adr[j*4+1] = cy0 * WW + cx1;
        adr[j*4+2] = cy1 * WW + cx0;
        adr[j*4+3] = cy1 * WW + cx1;
        wgt[j*4+0] = wx0 * wy0;
        wgt[j*4+1] = wx1 * wy0;
        wgt[j*4+2] = wx0 * wy1;
        wgt[j*4+3] = wx1 * wy1;
    }

    // ---- phase 2: issue all 16 fp16 gathers back-to-back (cached!) ----
    __half tvh[16];
#pragma unroll
    for (int t = 0; t < 16; ++t) tvh[t] = g2[adr[t]];

    // ---- phase 3: independent streaming loads land under the gather latency ----
    float4 c0  = ntload4(i1 + p4);
    float4 c1  = ntload4(i1 + HW + p4);
    float4 c2  = ntload4(i1 + 2 * HW + p4);
    float4 vm4 = ntload4(vm + p4);
    float4 ev4[CC];
#pragma unroll
    for (int c = 0; c < CC; ++c) ev4[c] = ntload4(evb + c * HW + p4);

    float g1a[4] = {
        0.299f * c0.x + 0.587f * c1.x + 0.114f * c2.x,
        0.299f * c0.y + 0.587f * c1.y + 0.114f * c2.y,
        0.299f * c0.z + 0.587f * c1.z + 0.114f * c2.z,
        0.299f * c0.w + 0.587f * c1.w + 0.114f * c2.w };
    float vma[4] = { vm4.x, vm4.y, vm4.z, vm4.w };

    float acc[NST];
#pragma unroll
    for (int i = 0; i < NST; ++i) acc[i] = 0.0f;

    float posA[4], negA[4], posmA[4], negmA[4], mA[4];

#pragma unroll
    for (int j = 0; j < 4; ++j) {
        float warp = __half2float(tvh[j*4+0]) * wgt[j*4+0]
                   + __half2float(tvh[j*4+1]) * wgt[j*4+1]
                   + __half2float(tvh[j*4+2]) * wgt[j*4+2]
                   + __half2float(tvh[j*4+3]) * wgt[j*4+3];

        float nc  = fast_tanh5(warp - g1a[j]);
        float pos = fmaxf(nc, 0.0f);
        float neg = fmaxf(-nc, 0.0f);
        posA[j] = pos;
        negA[j] = neg;

        float fx = fxa[j], fy = fya[j];
        float m = ((fx * fx + fy * fy) > 0.01f) ? vma[j] : 0.0f;
        mA[j] = m;
        float posm = pos * m;
        float negm = neg * m;
        posmA[j] = posm;
        negmA[j] = negm;
        acc[1] += m;
        acc[2] += posm;
        acc[3] += negm;
        acc[4] += posm * posm;
        acc[5] += negm * negm;
    }

#pragma unroll
    for (int c = 0; c < CC; ++c) {
        const float ga[4] = { ev4[c].x, ev4[c].y, ev4[c].z, ev4[c].w };
#pragma unroll
        for (int j = 0; j < 4; ++j) {
            float pm = mixc(c, posmA[j], negmA[j]);   // pos*neg==0 -> exact
            float gm = ga[j] * mA[j];
            acc[0]      += fabsf(pm - gm);
            acc[6 + c]  += gm;
            acc[11 + c] += gm * gm;
            acc[16 + c] += pm * gm;
        }
    }

    // ---- pred stores via lane-neighbor shuffle (nontemporal) ----
    const int lane = tid & 63;
    float npos[3], nneg[3];
#pragma unroll
    for (int j = 0; j < 3; ++j) {
        npos[j] = __shfl_down(posA[j], 1, 64);
        nneg[j] = __shfl_down(negA[j], 1, 64);
    }

#pragma unroll
    for (int c = 0; c < CC; ++c) {
        float* ob = po + c * HW + P + 4 * tid;
        if (lane < 63) {
            float4 v;
            v.x = mixc(c, posA[3], negA[3]);
            v.y = mixc(c, npos[0], nneg[0]);
            v.z = mixc(c, npos[1], nneg[1]);
            v.w = mixc(c, npos[2], nneg[2]);
            ntstore4(ob + 3, v);
        } else {
            ntstore1(ob + 3, mixc(c, posA[3], negA[3]));   // wave seam: own px3
        }
        if (lane == 0) {                          // wave/block seam: own px0..2
            ntstore1(ob + 0, mixc(c, posA[0], negA[0]));
            ntstore1(ob + 1, mixc(c, posA[1], negA[1]));
            ntstore1(ob + 2, mixc(c, posA[2], negA[2]));
        }
    }

    // ---- wave reduce on the VALU (DPP), result in lane 63 ----
    const int wid = tid >> 6;
#pragma unroll
    for (int i = 0; i < NST; ++i) acc[i] = wave_sum_dpp(acc[i]);
    if (lane == 63) {
#pragma unroll
        for (int i = 0; i < NST; ++i) sdata[wid][i] = acc[i];
    }

    __syncthreads();

    // ---- per-block partials: plain coalesced stores, NO atomics ----
    if (tid < NST) {
        float s = sdata[0][tid] + sdata[1][tid] + sdata[2][tid] + sdata[3][tid];
        partial[(size_t)(b * NBLK + bx) * 32 + tid] = s;
    }
}

__global__ void k_reduce(const float* __restrict__ partial, double* __restrict__ stats) {
    // one block per (b, stat-index): 8*21 = 168 blocks of 64 threads
    int bi = blockIdx.x;
    int b = bi / NST;
    int i = bi - b * NST;
    int t = threadIdx.x;
    double s = 0.0;
    for (int k = t; k < NBLK; k += 64)
        s += (double)partial[(size_t)(b * NBLK + k) * 32 + i];
    for (int off = 32; off > 0; off >>= 1) s += __shfl_down(s, off, 64);
    if (t == 0) stats[b * NST + i] = s;
}

__global__ void k_final(const double* __restrict__ stats, float* __restrict__ out) {
    int t = threadIdx.x;  // 64 threads
    double contrib = 0.0;
    if (t < BB * CC) {
        int b = t / CC;
        int c = t - b * CC;
        const double* s = stats + b * NST;
        const double wA[CC] = { 1.0, 0.0, 0.25, 0.50, 0.75 };
        const double wB[CC] = { 0.0, 1.0, 0.75, 0.50, 0.25 };
        double a = wA[c], bb = wB[c];
        double Sp  = a * s[2] + bb * s[3];
        double Spp = a * a * s[4] + bb * bb * s[5];   // cross term exactly 0
        double Sg  = s[6 + c];
        double Sgg = s[11 + c];
        double Spg = s[16 + c];
        const double N = (double)HW;
        double num  = Spg - Sp * Sg / N;
        double varp = Spp - Sp * Sp / N; if (varp < 0.0) varp = 0.0;
        double varg = Sgg - Sg * Sg / N; if (varg < 0.0) varg = 0.0;
        double den  = sqrt(varp) * sqrt(varg) + 1e-6;
        double corr = num / den;
        bool valid = s[1] > 0.0;
        contrib = valid ? (1.0 - corr) : 0.0;
    }
    for (int off = 32; off > 0; off >>= 1) contrib += __shfl_down(contrib, off, 64);
    if (t == 0) {
        double msum_total = 0.0, l1sum = 0.0;
        for (int b = 0; b < BB; ++b) {
            msum_total += stats[b * NST + 1];
            l1sum      += stats[b * NST + 0];
        }
        double mask_sum = (double)CC * msum_total + 1e-6;
        double l1_loss = l1sum / mask_sum;
        double corr_loss = contrib / (double)(BB * CC);
        out[0] = (float)(l1_loss + 0.5 * corr_loss);
    }
}

extern "C" void kernel_launch(void* const* d_in, const int* in_sizes, int n_in,
                              void* d_out, int out_size, void* d_ws, size_t ws_size,
                              hipStream_t stream) {
    const float* img1  = (const float*)d_in[0];
    const float* img2  = (const float*)d_in[1];
    const float* flow  = (const float*)d_in[2];
    const float* ev    = (const float*)d_in[3];
    const float* vmask = (const float*)d_in[4];
    float* out = (float*)d_out;

    double* stats   = (double*)d_ws;
    float*  partial = (float*)((char*)d_ws + PARTIAL_OFFSET);
    __half* gray2h  = (__half*)((char*)d_ws + GRAY2_OFFSET);

    k_gray2<<<1200, 256, 0, stream>>>(img2, gray2h);              // 8px/thread

    k_main<<<2400, 256, 0, stream>>>(img1, flow, ev, vmask, gray2h, out + 1, partial);

    k_reduce<<<BB * NST, 64, 0, stream>>>(partial, stats);

    k_final<<<1, 64, 0, stream>>>(stats, out);
}

// Round 18
// 42.830 us; speedup vs baseline: 1.2482x; 1.2482x over previous
//
#include <hip/hip_runtime.h>
#include <hip/hip_fp16.h>
#include <math.h>

#define BB 8
#define HH 480
#define WW 640
#define CC 5
#define HW (HH * WW)
#define NBLK 300   // k_main blocks per image
#define NST 21     // accumulators per block

// d_ws layout:
// [0 .. 4096)                  : stats doubles: stats[b*NST + i]
// [PARTIAL_OFFSET, +2400*32*4) : per-block float partials [b*NBLK+bx][32]
// [GRAY2_OFFSET, +BB*HW*2)     : fp16 gray2 planes
// stat indices per b:
//  0=l1  1=mask  2=Sposm  3=Snegm  4=Sposm2  5=Snegm2
//  6..10 = Sgm[c]   11..15 = Sgm2[c]   16..20 = Spg[c]
#define PARTIAL_OFFSET 4096
#define GRAY2_OFFSET (PARTIAL_OFFSET + 2400 * 32 * 4)

__device__ __forceinline__ float fast_tanh5(float d) {
    // tanh(5d) = (1 - e^{-10d}) / (1 + e^{-10d})
    float ez = __expf(-10.0f * d);
    return (1.0f - ez) * __builtin_amdgcn_rcpf(1.0f + ez);
}

__device__ __forceinline__ float mixc(int c, float pos, float neg) {
    if (c == 0) return pos;
    if (c == 1) return neg;
    const float w = 0.25f * (float)(c - 1);
    return w * pos + (1.0f - w) * neg;
}

// Full-wave (64-lane) sum via DPP. Total lands in lane 63.
__device__ __forceinline__ float wave_sum_dpp(float v) {
    v += __int_as_float(__builtin_amdgcn_update_dpp(0, __float_as_int(v), 0x111, 0xf, 0xf, false));
    v += __int_as_float(__builtin_amdgcn_update_dpp(0, __float_as_int(v), 0x112, 0xf, 0xf, false));
    v += __int_as_float(__builtin_amdgcn_update_dpp(0, __float_as_int(v), 0x114, 0xf, 0xf, false));
    v += __int_as_float(__builtin_amdgcn_update_dpp(0, __float_as_int(v), 0x118, 0xf, 0xf, false));
    v += __int_as_float(__builtin_amdgcn_update_dpp(0, __float_as_int(v), 0x142, 0xa, 0xf, false));
    v += __int_as_float(__builtin_amdgcn_update_dpp(0, __float_as_int(v), 0x143, 0xc, 0xf, false));
    return v;
}

// 1200 blocks, XCD-swizzled: b = blk&7 -> all blocks of image b on XCD b.
// Each thread: 8 px -> fp16 gray2.
__global__ __launch_bounds__(256) void k_gray2(const float* __restrict__ img2,
                                               __half* __restrict__ gray2h) {
    const int phys = blockIdx.x;
    const int b = phys & 7;
    const int j = phys >> 3;                       // [0,150)
    const int p8 = j * 2048 + threadIdx.x * 8;     // plane offset, 8 px
    const float* src = img2 + (size_t)b * 3 * HW + p8;
    float4 r0 = *(const float4*)(src);
    float4 r1 = *(const float4*)(src + 4);
    float4 g0 = *(const float4*)(src + HW);
    float4 g1 = *(const float4*)(src + HW + 4);
    float4 b0 = *(const float4*)(src + 2 * HW);
    float4 b1 = *(const float4*)(src + 2 * HW + 4);
    __half o[8];
    o[0] = __float2half(0.299f * r0.x + 0.587f * g0.x + 0.114f * b0.x);
    o[1] = __float2half(0.299f * r0.y + 0.587f * g0.y + 0.114f * b0.y);
    o[2] = __float2half(0.299f * r0.z + 0.587f * g0.z + 0.114f * b0.z);
    o[3] = __float2half(0.299f * r0.w + 0.587f * g0.w + 0.114f * b0.w);
    o[4] = __float2half(0.299f * r1.x + 0.587f * g1.x + 0.114f * b1.x);
    o[5] = __float2half(0.299f * r1.y + 0.587f * g1.y + 0.114f * b1.y);
    o[6] = __float2half(0.299f * r1.z + 0.587f * g1.z + 0.114f * b1.z);
    o[7] = __float2half(0.299f * r1.w + 0.587f * g1.w + 0.114f * b1.w);
    *(uint4*)(gray2h + (size_t)b * HW + p8) = *(const uint4*)o;
}

// 2400 blocks 1D, XCD-swizzled: b = blk&7, bx = blk>>3.
__global__ __launch_bounds__(256, 2) void k_main(
    const float* __restrict__ img1, const float* __restrict__ flow,
    const float* __restrict__ ev, const float* __restrict__ vmask,
    const __half* __restrict__ gray2h, float* __restrict__ pred_out,
    float* __restrict__ partial)
{
    const int b  = blockIdx.x & 7;
    const int bx = blockIdx.x >> 3;               // [0,300)
    const float* i1  = img1  + (size_t)b * 3 * HW;
    const float* fl  = flow  + (size_t)b * 2 * HW;
    const float* evb = ev    + (size_t)b * CC * HW;
    const float* vm  = vmask + (size_t)b * HW;
    const __half* g2 = gray2h + (size_t)b * HW;
    float* po = pred_out + (size_t)b * CC * HW;   // NOTE: 4B-aligned only (out+1)

    const int tid = threadIdx.x;
    const int P   = bx * 1024;                    // block owns px [P, P+1024)
    const int p4  = P + 4 * tid;                  // 4 px, same row
    const int py  = p4 / WW;
    const int px0 = p4 - py * WW;

    __shared__ float sdata[4][NST];

    // ---- phase 1: flow loads (gather addresses depend only on these) ----
    float4 fx4 = *(const float4*)(fl + p4);
    float4 fy4 = *(const float4*)(fl + HW + p4);

    float fxa[4] = { fx4.x, fx4.y, fx4.z, fx4.w };
    float fya[4] = { fy4.x, fy4.y, fy4.z, fy4.w };

    int   adr[16];
    float wgt[16];
#pragma unroll
    for (int j = 0; j < 4; ++j) {
        float fx = fxa[j], fy = fya[j];
        float x = (float)(px0 + j) + fx;
        float y = (float)py + fy;
        float x0f = floorf(x);
        float y0f = floorf(y);
        float wx = x - x0f;
        float wy = y - y0f;
        int x0 = (int)x0f, y0 = (int)y0f;
        int x1 = x0 + 1,   y1 = y0 + 1;
        int cx0 = min(max(x0, 0), WW - 1);
        int cx1 = min(max(x1, 0), WW - 1);
        int cy0 = min(max(y0, 0), HH - 1);
        int cy1 = min(max(y1, 0), HH - 1);
        float wx0 = (1.0f - wx) * ((x0 >= 0 && x0 < WW) ? 1.0f : 0.0f);
        float wx1 = wx          * ((x1 >= 0 && x1 < WW) ? 1.0f : 0.0f);
        float wy0 = (1.0f - wy) * ((y0 >= 0 && y0 < HH) ? 1.0f : 0.0f);
        float wy1 = wy          * ((y1 >= 0 && y1 < HH) ? 1.0f : 0.0f);
        adr[j*4+0] = cy0 * WW + cx0;
        adr[j*4+1] = cy0 * WW + cx1;
        adr[j*4+2] = cy1 * WW + cx0;
        adr[j*4+3] = cy1 * WW + cx1;
        wgt[j*4+0] = wx0 * wy0;
        wgt[j*4+1] = wx1 * wy0;
        wgt[j*4+2] = wx0 * wy1;
        wgt[j*4+3] = wx1 * wy1;
    }

    // ---- phase 2: issue all 16 fp16 gathers back-to-back ----
    __half tvh[16];
#pragma unroll
    for (int t = 0; t < 16; ++t) tvh[t] = g2[adr[t]];

    // ---- phase 3: independent loads land under the gather latency ----
    float4 c0  = *(const float4*)(i1 + p4);
    float4 c1  = *(const float4*)(i1 + HW + p4);
    float4 c2  = *(const float4*)(i1 + 2 * HW + p4);
    float4 vm4 = *(const float4*)(vm + p4);
    float4 ev4[CC];
#pragma unroll
    for (int c = 0; c < CC; ++c) ev4[c] = *(const float4*)(evb + c * HW + p4);

    float g1a[4] = {
        0.299f * c0.x + 0.587f * c1.x + 0.114f * c2.x,
        0.299f * c0.y + 0.587f * c1.y + 0.114f * c2.y,
        0.299f * c0.z + 0.587f * c1.z + 0.114f * c2.z,
        0.299f * c0.w + 0.587f * c1.w + 0.114f * c2.w };
    float vma[4] = { vm4.x, vm4.y, vm4.z, vm4.w };

    float acc[NST];
#pragma unroll
    for (int i = 0; i < NST; ++i) acc[i] = 0.0f;

    float posA[4], negA[4], posmA[4], negmA[4], mA[4];

#pragma unroll
    for (int j = 0; j < 4; ++j) {
        float warp = __half2float(tvh[j*4+0]) * wgt[j*4+0]
                   + __half2float(tvh[j*4+1]) * wgt[j*4+1]
                   + __half2float(tvh[j*4+2]) * wgt[j*4+2]
                   + __half2float(tvh[j*4+3]) * wgt[j*4+3];

        float nc  = fast_tanh5(warp - g1a[j]);
        float pos = fmaxf(nc, 0.0f);
        float neg = fmaxf(-nc, 0.0f);
        posA[j] = pos;
        negA[j] = neg;

        float fx = fxa[j], fy = fya[j];
        float m = ((fx * fx + fy * fy) > 0.01f) ? vma[j] : 0.0f;
        mA[j] = m;
        float posm = pos * m;
        float negm = neg * m;
        posmA[j] = posm;
        negmA[j] = negm;
        acc[1] += m;
        acc[2] += posm;
        acc[3] += negm;
        acc[4] += posm * posm;
        acc[5] += negm * negm;
    }

#pragma unroll
    for (int c = 0; c < CC; ++c) {
        const float ga[4] = { ev4[c].x, ev4[c].y, ev4[c].z, ev4[c].w };
#pragma unroll
        for (int j = 0; j < 4; ++j) {
            float pm = mixc(c, posmA[j], negmA[j]);   // pos*neg==0 -> exact
            float gm = ga[j] * mA[j];
            acc[0]      += fabsf(pm - gm);
            acc[6 + c]  += gm;
            acc[11 + c] += gm * gm;
            acc[16 + c] += pm * gm;
        }
    }

    // ---- pred stores via lane-neighbor shuffle ----
    const int lane = tid & 63;
    float npos[3], nneg[3];
#pragma unroll
    for (int j = 0; j < 3; ++j) {
        npos[j] = __shfl_down(posA[j], 1, 64);
        nneg[j] = __shfl_down(negA[j], 1, 64);
    }

#pragma unroll
    for (int c = 0; c < CC; ++c) {
        float* ob = po + c * HW + P + 4 * tid;
        if (lane < 63) {
            float4 v;
            v.x = mixc(c, posA[3], negA[3]);
            v.y = mixc(c, npos[0], nneg[0]);
            v.z = mixc(c, npos[1], nneg[1]);
            v.w = mixc(c, npos[2], nneg[2]);
            *(float4*)(ob + 3) = v;
        } else {
            ob[3] = mixc(c, posA[3], negA[3]);   // wave seam: own px3 only
        }
        if (lane == 0) {                          // wave/block seam: own px0..2
            ob[0] = mixc(c, posA[0], negA[0]);
            ob[1] = mixc(c, posA[1], negA[1]);
            ob[2] = mixc(c, posA[2], negA[2]);
        }
    }

    // ---- wave reduce on the VALU (DPP), result in lane 63 ----
    const int wid = tid >> 6;
#pragma unroll
    for (int i = 0; i < NST; ++i) acc[i] = wave_sum_dpp(acc[i]);
    if (lane == 63) {
#pragma unroll
        for (int i = 0; i < NST; ++i) sdata[wid][i] = acc[i];
    }

    __syncthreads();

    // ---- per-block partials: plain coalesced stores, NO atomics ----
    if (tid < NST) {
        float s = sdata[0][tid] + sdata[1][tid] + sdata[2][tid] + sdata[3][tid];
        partial[(size_t)(b * NBLK + bx) * 32 + tid] = s;
    }
}

__global__ void k_reduce(const float* __restrict__ partial, double* __restrict__ stats) {
    // one block per (b, stat-index): 8*21 = 168 blocks of 64 threads
    int bi = blockIdx.x;
    int b = bi / NST;
    int i = bi - b * NST;
    int t = threadIdx.x;
    double s = 0.0;
    for (int k = t; k < NBLK; k += 64)
        s += (double)partial[(size_t)(b * NBLK + k) * 32 + i];
    for (int off = 32; off > 0; off >>= 1) s += __shfl_down(s, off, 64);
    if (t == 0) stats[b * NST + i] = s;
}

__global__ void k_final(const double* __restrict__ stats, float* __restrict__ out) {
    int t = threadIdx.x;  // 64 threads
    double contrib = 0.0;
    if (t < BB * CC) {
        int b = t / CC;
        int c = t - b * CC;
        const double* s = stats + b * NST;
        const double wA[CC] = { 1.0, 0.0, 0.25, 0.50, 0.75 };
        const double wB[CC] = { 0.0, 1.0, 0.75, 0.50, 0.25 };
        double a = wA[c], bb = wB[c];
        double Sp  = a * s[2] + bb * s[3];
        double Spp = a * a * s[4] + bb * bb * s[5];   // cross term exactly 0
        double Sg  = s[6 + c];
        double Sgg = s[11 + c];
        double Spg = s[16 + c];
        const double N = (double)HW;
        double num  = Spg - Sp * Sg / N;
        double varp = Spp - Sp * Sp / N; if (varp < 0.0) varp = 0.0;
        double varg = Sgg - Sg * Sg / N; if (varg < 0.0) varg = 0.0;
        double den  = sqrt(varp) * sqrt(varg) + 1e-6;
        double corr = num / den;
        bool valid = s[1] > 0.0;
        contrib = valid ? (1.0 - corr) : 0.0;
    }
    for (int off = 32; off > 0; off >>= 1) contrib += __shfl_down(contrib, off, 64);
    if (t == 0) {
        double msum_total = 0.0, l1sum = 0.0;
        for (int b = 0; b < BB; ++b) {
            msum_total += stats[b * NST + 1];
            l1sum      += stats[b * NST + 0];
        }
        double mask_sum = (double)CC * msum_total + 1e-6;
        double l1_loss = l1sum / mask_sum;
        double corr_loss = contrib / (double)(BB * CC);
        out[0] = (float)(l1_loss + 0.5 * corr_loss);
    }
}

extern "C" void kernel_launch(void* const* d_in, const int* in_sizes, int n_in,
                              void* d_out, int out_size, void* d_ws, size_t ws_size,
                              hipStream_t stream) {
    const float* img1  = (const float*)d_in[0];
    const float* img2  = (const float*)d_in[1];
    const float* flow  = (const float*)d_in[2];
    const float* ev    = (const float*)d_in[3];
    const float* vmask = (const float*)d_in[4];
    float* out = (float*)d_out;

    double* stats   = (double*)d_ws;
    float*  partial = (float*)((char*)d_ws + PARTIAL_OFFSET);
    __half* gray2h  = (__half*)((char*)d_ws + GRAY2_OFFSET);

    k_gray2<<<1200, 256, 0, stream>>>(img2, gray2h);              // 8px/thread

    k_main<<<2400, 256, 0, stream>>>(img1, flow, ev, vmask, gray2h, out + 1, partial);

    k_reduce<<<BB * NST, 64, 0, stream>>>(partial, stats);

    k_final<<<1, 64, 0, stream>>>(stats, out);
}